// Round 11
// baseline (779.783 us; speedup 1.0000x reference)
//
#include <hip/hip_runtime.h>
#include <math.h>

#define FN 512
#define TPB 256
#define NIMG 256
#define NBATCH 8
#define NCH 32
#define NBINS 257
#define WACOLS 257   // Hermitian half-spectrum columns u=0..256
#define WBS 256      // Wb row stride (complex); used width = cutoff
#define SPITCH 516   // staging/exchange row pitch (complex)

typedef unsigned long long ull;

__device__ __forceinline__ float2 cadd(float2 a, float2 b) { return make_float2(a.x + b.x, a.y + b.y); }
__device__ __forceinline__ float2 csub(float2 a, float2 b) { return make_float2(a.x - b.x, a.y - b.y); }
__device__ __forceinline__ float2 cmul(float2 a, float2 b) {
  return make_float2(fmaf(a.x, b.x, -a.y * b.y), fmaf(a.x, b.y, a.y * b.x));
}
template<bool INV>
__device__ __forceinline__ float2 cmul_s(float2 a, float2 w) {
  if (!INV) return make_float2(fmaf(a.x, w.x, -a.y * w.y), fmaf(a.x, w.y,  a.y * w.x));
  else      return make_float2(fmaf(a.x, w.x,  a.y * w.y), fmaf(a.y, w.x, -a.x * w.y));
}
__device__ __forceinline__ float2 cexpm(float ang) {
  float s, c;
  __sincosf(ang, &s, &c);
  return make_float2(c, s);
}
template<bool INV>
__device__ __forceinline__ float2 mulpmi(float2 a) {
  return INV ? make_float2(-a.y, a.x) : make_float2(a.y, -a.x);
}

template<bool INV>
__device__ __forceinline__ void dft8(float2 r[8]) {
  const float C = 0.70710678118654752440f;
  float2 t0 = cadd(r[0], r[4]), t1 = csub(r[0], r[4]);
  float2 t2 = cadd(r[2], r[6]), t3 = mulpmi<INV>(csub(r[2], r[6]));
  float2 E0 = cadd(t0, t2), E1 = cadd(t1, t3), E2 = csub(t0, t2), E3 = csub(t1, t3);
  float2 u0 = cadd(r[1], r[5]), u1 = csub(r[1], r[5]);
  float2 u2 = cadd(r[3], r[7]), u3 = mulpmi<INV>(csub(r[3], r[7]));
  float2 O0 = cadd(u0, u2), O1 = cadd(u1, u3), O2 = csub(u0, u2), O3 = csub(u1, u3);
  float2 O1w, O2w, O3w;
  if (!INV) {
    O1w = make_float2(C * (O1.x + O1.y), C * (O1.y - O1.x));
    O2w = make_float2(O2.y, -O2.x);
    O3w = make_float2(C * (O3.y - O3.x), -C * (O3.x + O3.y));
  } else {
    O1w = make_float2(C * (O1.x - O1.y), C * (O1.y + O1.x));
    O2w = make_float2(-O2.y, O2.x);
    O3w = make_float2(-C * (O3.x + O3.y), C * (O3.x - O3.y));
  }
  r[0] = cadd(E0, O0); r[1] = cadd(E1, O1w); r[2] = cadd(E2, O2w); r[3] = cadd(E3, O3w);
  r[4] = csub(E0, O0); r[5] = csub(E1, O1w); r[6] = csub(E2, O2w); r[7] = csub(E3, O3w);
}

__device__ __forceinline__ int swz(int q) {
  int b = (q >> 6) & 7;
  return q ^ b ^ ((b & 4) << 1);
}

#define TWOPI 6.2831853071795864769f

__device__ __forceinline__ void build_tw(int t, float2 tw512[7], float2 tw64[7]) {
  float2 w1 = cexpm(-TWOPI * (float)t * (1.0f / 512.0f));
  tw512[0] = w1;
  #pragma unroll
  for (int k = 1; k < 7; ++k) tw512[k] = cmul(tw512[k - 1], w1);
  float2 v1 = cexpm(-TWOPI * (float)(t & 7) * (1.0f / 64.0f));
  tw64[0] = v1;
  #pragma unroll
  for (int e = 1; e < 7; ++e) tw64[e] = cmul(tw64[e - 1], v1);
}

// Dual 512-pt FFT, natural in (reg j = x[t+64j]) -> digit-rev out
// (reg f = X[64f+8(t&7)+(t>>3)]). Wave-private exchange, no barriers.
template<bool INV>
__device__ __forceinline__ void fft512_dif2(float2 rA[8], float2 rB[8],
                                            float2* __restrict__ LA, float2* __restrict__ LB,
                                            int t, const float2 tw512[7], const float2 tw64[7]) {
  dft8<INV>(rA);
  dft8<INV>(rB);
  #pragma unroll
  for (int k = 1; k < 8; ++k) {
    rA[k] = cmul_s<INV>(rA[k], tw512[k - 1]);
    rB[k] = cmul_s<INV>(rB[k], tw512[k - 1]);
  }
  #pragma unroll
  for (int k = 0; k < 8; ++k) { LA[swz(64 * k + t)] = rA[k]; LB[swz(64 * k + t)] = rB[k]; }
  const int base = 64 * (t >> 3) + (t & 7);
  #pragma unroll
  for (int d = 0; d < 8; ++d) rA[d] = LA[swz(base + 8 * d)];
  #pragma unroll
  for (int d = 0; d < 8; ++d) rB[d] = LB[swz(base + 8 * d)];
  dft8<INV>(rA);
  dft8<INV>(rB);
  #pragma unroll
  for (int e = 1; e < 8; ++e) {
    rA[e] = cmul_s<INV>(rA[e], tw64[e - 1]);
    rB[e] = cmul_s<INV>(rB[e], tw64[e - 1]);
  }
  #pragma unroll
  for (int e = 0; e < 8; ++e) { LA[swz(base + 8 * e)] = rA[e]; LB[swz(base + 8 * e)] = rB[e]; }
  #pragma unroll
  for (int m = 0; m < 8; ++m) rA[m] = LA[swz(8 * t + m)];
  #pragma unroll
  for (int m = 0; m < 8; ++m) rB[m] = LB[swz(8 * t + m)];
  dft8<INV>(rA);
  dft8<INV>(rB);
}

// Dual mirror (DIT): digit-rev in -> natural out. INV=true gives 512*IDFT.
template<bool INV>
__device__ __forceinline__ void fft512_dit2(float2 rA[8], float2 rB[8],
                                            float2* __restrict__ LA, float2* __restrict__ LB,
                                            int t, const float2 tw64[7], float2 w0, float2 st) {
  dft8<INV>(rA);
  dft8<INV>(rB);
  #pragma unroll
  for (int c = 1; c < 8; ++c) {
    rA[c] = cmul_s<INV>(rA[c], tw64[c - 1]);
    rB[c] = cmul_s<INV>(rB[c], tw64[c - 1]);
  }
  #pragma unroll
  for (int c = 0; c < 8; ++c) { LA[swz(8 * t + c)] = rA[c]; LB[swz(8 * t + c)] = rB[c]; }
  const int base = 64 * (t >> 3) + (t & 7);
  #pragma unroll
  for (int e = 0; e < 8; ++e) rA[e] = LA[swz(base + 8 * e)];
  #pragma unroll
  for (int e = 0; e < 8; ++e) rB[e] = LB[swz(base + 8 * e)];
  dft8<INV>(rA);
  dft8<INV>(rB);
  {
    float2 w = w0;
    #pragma unroll
    for (int d = 0; d < 8; ++d) {
      rA[d] = cmul(rA[d], w);
      rB[d] = cmul(rB[d], w);
      w = cmul(w, st);
    }
  }
  #pragma unroll
  for (int d = 0; d < 8; ++d) { LA[swz(base + 8 * d)] = rA[d]; LB[swz(base + 8 * d)] = rB[d]; }
  #pragma unroll
  for (int j = 0; j < 8; ++j) rA[j] = LA[swz(64 * j + t)];
  #pragma unroll
  for (int j = 0; j < 8; ++j) rB[j] = LB[swz(64 * j + t)];
  dft8<INV>(rA);
  dft8<INV>(rB);
}

// Single FFT
template<bool INV>
__device__ __forceinline__ void fft512_dif(float2 r[8], float2* __restrict__ L, int t,
                                           const float2 tw512[7], const float2 tw64[7]) {
  dft8<INV>(r);
  #pragma unroll
  for (int k = 1; k < 8; ++k) r[k] = cmul_s<INV>(r[k], tw512[k - 1]);
  #pragma unroll
  for (int k = 0; k < 8; ++k) L[swz(64 * k + t)] = r[k];
  const int base = 64 * (t >> 3) + (t & 7);
  #pragma unroll
  for (int d = 0; d < 8; ++d) r[d] = L[swz(base + 8 * d)];
  dft8<INV>(r);
  #pragma unroll
  for (int e = 1; e < 8; ++e) r[e] = cmul_s<INV>(r[e], tw64[e - 1]);
  #pragma unroll
  for (int e = 0; e < 8; ++e) L[swz(base + 8 * e)] = r[e];
  #pragma unroll
  for (int m = 0; m < 8; ++m) r[m] = L[swz(8 * t + m)];
  dft8<INV>(r);
}

__device__ __forceinline__ int ringc(int u) { return (u < 256) ? (u + 1) : (512 - u); }

// Pass 1: two real rows packed per complex FFT (dual-interleaved pairs) -> Hermitian
// unpack -> store half spectrum transposed W[u][h], u <= ulim. 16 image rows/block.
__global__ __launch_bounds__(TPB, 4) void k_fwd_real(const float* __restrict__ x,
                                                     float2* __restrict__ W,
                                                     int img0, int img_stride,
                                                     const int* __restrict__ cut, int use_cut) {
  __shared__ float2 stg[8][SPITCH];
  const int g = threadIdx.x >> 6, t = threadIdx.x & 63;
  const int li = blockIdx.x >> 5;
  const int R0 = (blockIdx.x & 31) * 16;
  const int img = img0 + li * img_stride;
  int ulim = 256;
  if (use_cut) ulim = cut[img >> 5];
  const float* __restrict__ base = x + (size_t)img * (FN * FN);
  float2 tw512[7], tw64[7];
  build_tw(t, tw512, tw64);
  {
    const float* __restrict__ raA = base + (size_t)(R0 + 2 * g) * FN;
    const float* __restrict__ rbA = raA + FN;
    const float* __restrict__ raB = base + (size_t)(R0 + 8 + 2 * g) * FN;
    const float* __restrict__ rbB = raB + FN;
    float2 rA[8], rB[8];
    #pragma unroll
    for (int j = 0; j < 8; ++j) {
      rA[j] = make_float2(raA[t + 64 * j], rbA[t + 64 * j]);
      rB[j] = make_float2(raB[t + 64 * j], rbB[t + 64 * j]);
    }
    fft512_dif2<false>(rA, rB, &stg[g][0], &stg[4 + g][0], t, tw512, tw64);
    #pragma unroll
    for (int f = 0; f < 8; ++f) {
      int p = 64 * f + 8 * (t & 7) + (t >> 3);
      stg[g][p] = rA[f];
      stg[4 + g][p] = rB[f];
    }
  }
  __syncthreads();
  float2* __restrict__ dst = W + (size_t)li * (WACOLS * FN);
  const int pr = threadIdx.x & 7;
  const int u0 = threadIdx.x >> 3;
  #pragma unroll
  for (int kk = 0; kk < 8; ++kk) {
    int u = u0 + 32 * kk;
    if (u <= ulim) {
      float2 Za = stg[pr][u];
      float2 Zb = stg[pr][(512 - u) & 511];
      float2 Fa = make_float2(0.5f * (Za.x + Zb.x), 0.5f * (Za.y - Zb.y));
      float2 Fb = make_float2(0.5f * (Za.y + Zb.y), 0.5f * (Zb.x - Za.x));
      float4* d4 = (float4*)(dst + (size_t)u * FN + R0 + 2 * pr);
      *d4 = make_float4(Fa.x, Fa.y, Fb.x, Fb.y);
    }
  }
  if (!use_cut && threadIdx.x < 8) {               // u=256 Nyquist (prepass only)
    float2 Z = stg[threadIdx.x][256];
    float4* d4 = (float4*)(dst + (size_t)256 * FN + R0 + 2 * threadIdx.x);
    *d4 = make_float4(Z.x, 0.f, Z.y, 0.f);
  }
}

// Pre-pass: ring energies (fixed-point, order-invariant) -> cutoffs.
__global__ __launch_bounds__(TPB) void k_ring(const float2* __restrict__ W1p, ull* __restrict__ bins) {
  __shared__ float2 ex[4][FN];
  __shared__ ull lbins[NBINS];
  const int g = threadIdx.x >> 6, t = threadIdx.x & 63;
  for (int i = threadIdx.x; i < NBINS; i += TPB) lbins[i] = 0;
  __syncthreads();
  const int li = blockIdx.x / 33;
  const int U0 = (blockIdx.x % 33) * 8;
  const float2* __restrict__ src = W1p + (size_t)li * (WACOLS * FN);
  float2 tw512[7], tw64[7];
  build_tw(t, tw512, tw64);
  #pragma unroll
  for (int s = 0; s < 2; ++s) {
    const int u = U0 + 4 * s + g;
    if (u > 256) continue;
    const float2* __restrict__ row = src + (size_t)u * FN;
    float2 r[8];
    #pragma unroll
    for (int j = 0; j < 8; ++j) r[j] = row[t + 64 * j];
    fft512_dif<false>(r, &ex[g][0], t, tw512, tw64);
    const int cu = ringc(u);
    const bool mir = (u >= 1 && u <= 255);
    const int cmu = mir ? ringc(512 - u) : 0;
    #pragma unroll
    for (int f = 0; f < 8; ++f) {
      int v = 64 * f + 8 * (t & 7) + (t >> 3);
      float e = fmaf(r[f].x, r[f].x, r[f].y * r[f].y);
      ull q = (ull)((double)e * 1048576.0);
      atomicAdd(&lbins[max(cu, ringc(v))], q);
      if (mir) atomicAdd(&lbins[max(cmu, ringc((512 - v) & 511))], q);
    }
  }
  __syncthreads();
  for (int i = threadIdx.x; i < NBINS; i += TPB)
    if (lbins[i]) atomicAdd(&bins[(size_t)li * NBINS + i], lbins[i]);
}

__global__ __launch_bounds__(64) void k_cutoff(const ull* __restrict__ bins, int* __restrict__ cut) {
  int b = threadIdx.x;
  if (b >= NBATCH) return;
  double tot = 0.0;
  for (int r = 0; r < NBINS; ++r) tot += (double)bins[b * NBINS + r];
  double target = 0.5 * tot;
  double cum = 0.0;
  int c = 5;
  bool found = false;
  for (int r = 0; r <= 255; ++r) {
    cum += (double)bins[b * NBINS + r];
    if (r >= 1 && !found && cum >= target) { c = r; found = true; }
  }
  cut[b] = c;
}

// Pass 2 (symmetric-mask primaries u in [0,cut]): column FFT -> extract F(cut,u),
// F(NC,u) -> symmetric lvs mask (scaled 1/512) -> inverse column FFT.
// u<cut -> Wb[h][u]; u==cut -> Abuf[h]. NC = 512-cut.
// The LAST block of each image (device atomic counter) also computes bvec in-place
// (folded k_gv): deterministic values, order-independent.
__global__ __launch_bounds__(TPB, 4) void k_cols(const float2* __restrict__ Wa,
                                                 float2* __restrict__ Wb,
                                                 float2* __restrict__ Abuf,
                                                 float2* __restrict__ Bv,
                                                 float2* __restrict__ Fc,
                                                 float2* __restrict__ c4raw,
                                                 float2* __restrict__ bvec,
                                                 unsigned* __restrict__ cnt,
                                                 const int* __restrict__ cut, int img0) {
  __shared__ float2 stg[8][SPITCH];
  __shared__ int lastFlag;
  const int g = threadIdx.x >> 6, t = threadIdx.x & 63;
  const int li = blockIdx.x >> 5;
  const int U0 = (blockIdx.x & 31) * 8;
  const int img = img0 + li;
  const int cutoff = cut[img >> 5];
  const int NC = 512 - cutoff;
  if (U0 <= cutoff) {
    const float2* __restrict__ src = Wa + (size_t)li * (WACOLS * FN);
    float2 tw512[7], tw64[7];
    build_tw(t, tw512, tw64);
    const int tk = t >> 3, tc = t & 7;
    const float2 w0d = cexpm(TWOPI * (float)(tc * tk) * (1.0f / 512.0f));
    const float2 std = cexpm(TWOPI * (float)tk * (1.0f / 64.0f));
    const float sc = 1.0f / 512.0f;
    const int uA = U0 + g, uB = U0 + 4 + g;
    const float2* __restrict__ rowA = src + (size_t)uA * FN;
    const float2* __restrict__ rowB = src + (size_t)uB * FN;
    float2 rA[8], rB[8];
    #pragma unroll
    for (int j = 0; j < 8; ++j) { rA[j] = rowA[t + 64 * j]; rB[j] = rowB[t + 64 * j]; }
    float2* LA = &stg[g][0];
    float2* LB = &stg[4 + g][0];
    fft512_dif2<false>(rA, rB, LA, LB, t, tw512, tw64);
    const int vt = 8 * tc + tk;
    #pragma unroll
    for (int f = 0; f < 8; ++f) {
      int v = 64 * f + vt;
      if (v == cutoff) {
        if (uA < cutoff) Fc[li * 256 + uA] = rA[f];
        else if (uA == cutoff) c4raw[li] = rA[f];
        if (uB < cutoff) Fc[li * 256 + uB] = rB[f];
        else if (uB == cutoff) c4raw[li] = rB[f];
      }
      if (v == NC) {
        if (uA < cutoff) Bv[li * 256 + uA] = rA[f];
        if (uB < cutoff) Bv[li * 256 + uB] = rB[f];
      }
    }
    #pragma unroll
    for (int f = 0; f < 8; ++f) {
      int v = 64 * f + vt;
      bool lo = (v < cutoff) || (v > NC);
      rA[f] = lo ? make_float2(rA[f].x * sc, rA[f].y * sc) : make_float2(0.f, 0.f);
      rB[f] = lo ? make_float2(rB[f].x * sc, rB[f].y * sc) : make_float2(0.f, 0.f);
    }
    fft512_dit2<true>(rA, rB, LA, LB, t, tw64, w0d, std);
    const bool aA = (uA == cutoff), aB = (uB == cutoff);
    #pragma unroll
    for (int j = 0; j < 8; ++j) {
      int h = t + 64 * j;
      stg[g][h] = rA[j];
      stg[4 + g][h] = rB[j];
      if (aA) Abuf[li * 512 + h] = rA[j];
      if (aB) Abuf[li * 512 + h] = rB[j];
    }
    __syncthreads();
    float2* __restrict__ dst = Wb + (size_t)li * (512 * WBS);
    const int rl2 = threadIdx.x & 3;
    const int hg = threadIdx.x >> 2;
    #pragma unroll
    for (int kk = 0; kk < 8; ++kk) {
      int h = hg + 64 * kk;
      float2 a = stg[2 * rl2][h];
      float2 b = stg[2 * rl2 + 1][h];
      float4* d4 = (float4*)(dst + (size_t)h * WBS + U0 + 2 * rl2);
      *d4 = make_float4(a.x, a.y, b.x, b.y);
    }
  }
  // completion counter: all 32 blocks of this image participate
  if (threadIdx.x == 0) {
    __threadfence();
    unsigned old = atomicAdd(&cnt[img], 1u);
    lastFlag = (old == 31u) ? 1 : 0;
  }
  __syncthreads();
  if (lastFlag && threadIdx.x < 64) {
    __threadfence();                       // make others' Bv/Fc stores visible
    const int tt = threadIdx.x;
    const float s2 = 1.0f / (512.0f * 512.0f);
    float2 tw512[7], tw64[7];
    build_tw(tt, tw512, tw64);
    float2 r[8];
    #pragma unroll
    for (int j = 0; j < 8; ++j) {
      int u = tt + 64 * j;
      float2 gv = make_float2(0.f, 0.f);
      if (u < cutoff) {
        float2 b = Bv[li * 256 + u];
        gv = make_float2(b.x * s2, b.y * s2);
      } else if (u >= 513 - cutoff) {
        float2 F = Fc[li * 256 + (512 - u)];
        gv = make_float2(F.x * s2, -F.y * s2);
      }
      r[j] = gv;
    }
    fft512_dif<true>(r, &stg[0][0], tt, tw512, tw64);
    #pragma unroll
    for (int f = 0; f < 8; ++f) {
      int w = 64 * f + 8 * (tt & 7) + (tt >> 3);
      bvec[li * 512 + w] = r[f];
    }
  }
}

// Pass 3 (slim): one packed-row IFFT per wave (rows h1,h2). Hermitian-extend Wb,
// inverse FFT, add corrections d = ph*A' + wv*b, out = |x - low - d|.
__global__ __launch_bounds__(TPB, 4) void k_rows(const float2* __restrict__ Wb,
                                                 const float2* __restrict__ Abuf,
                                                 const float2* __restrict__ bvec,
                                                 const float2* __restrict__ c4raw,
                                                 const float* __restrict__ x,
                                                 float* __restrict__ out,
                                                 const int* __restrict__ cut, int img0) {
  __shared__ float2 ex[4][SPITCH];
  const int g = threadIdx.x >> 6, t = threadIdx.x & 63;
  const int li = blockIdx.x >> 6;
  const int H0 = (blockIdx.x & 63) * 8;
  const int img = img0 + li;
  const int cutoff = cut[img >> 5];
  const int NC = 512 - cutoff;
  const float2* __restrict__ wbase = Wb + (size_t)li * (512 * WBS);
  const float* __restrict__ xbase = x + (size_t)img * (FN * FN);
  float* __restrict__ obase = out + (size_t)img * (FN * FN);
  float2 tw512[7], tw64[7];
  build_tw(t, tw512, tw64);
  const float sc = 1.0f / 512.0f;
  const int h1 = H0 + 2 * g, h2 = h1 + 1;
  const float2* __restrict__ r1 = wbase + (size_t)h1 * WBS;
  const float2* __restrict__ r2 = wbase + (size_t)h2 * WBS;
  float2 r[8];
  #pragma unroll
  for (int j = 0; j < 8; ++j) {
    int u = t + 64 * j;
    float2 z;
    if (u < cutoff) {
      float2 m1 = r1[u], m2 = r2[u];
      z = make_float2(m1.x - m2.y, m1.y + m2.x);
    } else if (u > NC) {
      int um = 512 - u;
      float2 m1 = r1[um], m2 = r2[um];
      z = make_float2(m1.x + m2.y, -m1.y + m2.x);
    } else {
      z = make_float2(0.f, 0.f);
    }
    r[j] = make_float2(z.x * sc, z.y * sc);
  }
  fft512_dif<true>(r, &ex[g][0], t, tw512, tw64);
  // per-row correction scalars
  const float s2 = sc * sc;
  float2 cv = c4raw[li];
  const float2 c4 = make_float2(cv.x * s2, -cv.y * s2);
  float2 wv1 = cexpm(TWOPI * (float)((NC * h1) & 511) * (1.0f / 512.0f));
  float2 wv2 = cexpm(TWOPI * (float)((NC * h2) & 511) * (1.0f / 512.0f));
  float2 A1 = Abuf[li * 512 + h1], A2 = Abuf[li * 512 + h2];
  float2 A1p = cadd(make_float2(A1.x * sc, -A1.y * sc), cmul(c4, wv1));
  float2 A2p = cadd(make_float2(A2.x * sc, -A2.y * sc), cmul(c4, wv2));
  const int w0i = 8 * (t & 7) + (t >> 3);
  float2 ph = cexpm(TWOPI * (float)((NC * w0i) & 511) * (1.0f / 512.0f));
  const float2 s64 = cexpm(TWOPI * (float)((64 * (NC & 7)) & 511) * (1.0f / 512.0f));
  const float* __restrict__ x1 = xbase + (size_t)h1 * FN;
  const float* __restrict__ x2 = xbase + (size_t)h2 * FN;
  float* __restrict__ o1 = obase + (size_t)h1 * FN;
  float* __restrict__ o2 = obase + (size_t)h2 * FN;
  const float2* __restrict__ bp = bvec + li * 512;
  #pragma unroll
  for (int f = 0; f < 8; ++f) {
    int p = 64 * f + w0i;
    float2 bv = bp[p];
    float2 d1 = cadd(cmul(ph, A1p), cmul(wv1, bv));
    float2 d2 = cadd(cmul(ph, A2p), cmul(wv2, bv));
    float e1 = x1[p] - r[f].x - d1.x;
    float e2 = x2[p] - r[f].y - d2.x;
    o1[p] = sqrtf(fmaf(e1, e1, d1.y * d1.y));
    o2[p] = sqrtf(fmaf(e2, e2, d2.y * d2.y));
    ph = cmul(ph, s64);
  }
}

extern "C" void kernel_launch(void* const* d_in, const int* in_sizes, int n_in,
                              void* d_out, int out_size, void* d_ws, size_t ws_size,
                              hipStream_t stream) {
  const float* x = (const float*)d_in[0];
  float* out = (float*)d_out;
  char* ws = (char*)d_ws;

  size_t off = 0;
  ull* bins = (ull*)(ws + off);
  const size_t bins_bytes = (size_t)NBATCH * NBINS * sizeof(ull);      // 16448
  off += bins_bytes;
  unsigned* cnt = (unsigned*)(ws + off);
  const size_t cnt_bytes = (size_t)NIMG * sizeof(unsigned);            // 1024
  off += cnt_bytes;
  off = (off + 255) & ~(size_t)255;
  int* cut = (int*)(ws + off);
  off += 256;
  float2* W1p = (float2*)(ws + off);
  off += (size_t)NBATCH * WACOLS * FN * sizeof(float2);                // 8.4 MiB

  const size_t per_wa = (size_t)WACOLS * FN * sizeof(float2);          // ~1.03 MiB
  const size_t per_wb = (size_t)512 * WBS * sizeof(float2);            // 1 MiB
  const size_t per_side = (size_t)(512 + 512 + 256 + 256 + 8) * sizeof(float2);
  size_t avail = (ws_size > off) ? (ws_size - off) : 0;
  int K = (int)(avail / (per_wa + per_wb + per_side));
  if (K > 43) K = 43;   // 6 chunks; resident set ~150 MB, L3-safe
  if (K < 1) K = 1;
  float2* WA = (float2*)(ws + off);               off += (size_t)K * per_wa;
  float2* WB = (float2*)(ws + off);               off += (size_t)K * per_wb;
  float2* Abuf = (float2*)(ws + off);             off += (size_t)K * 512 * sizeof(float2);
  float2* bvec = (float2*)(ws + off);             off += (size_t)K * 512 * sizeof(float2);
  float2* Bv = (float2*)(ws + off);               off += (size_t)K * 256 * sizeof(float2);
  float2* Fc = (float2*)(ws + off);               off += (size_t)K * 256 * sizeof(float2);
  float2* c4raw = (float2*)(ws + off);            off += (size_t)K * 8 * sizeof(float2);

  // zero bins + per-image completion counters in one captured memset
  hipMemsetAsync(bins, 0, bins_bytes + cnt_bytes, stream);

  // Pre-pass on the 8 channel-0 images: half-spectrum + ring energies + cutoffs.
  hipLaunchKernelGGL(k_fwd_real, dim3(NBATCH * 32), dim3(TPB), 0, stream, x, W1p, 0, NCH, cut, 0);
  hipLaunchKernelGGL(k_ring,     dim3(NBATCH * 33), dim3(TPB), 0, stream, W1p, bins);
  hipLaunchKernelGGL(k_cutoff,   dim3(1),           dim3(64),  0, stream, bins, cut);

  // Main pipeline, chunked for L3 residency. k_gv folded into k_cols (last block).
  for (int c0 = 0; c0 < NIMG; c0 += K) {
    int nk = (NIMG - c0 < K) ? (NIMG - c0) : K;
    hipLaunchKernelGGL(k_fwd_real, dim3(nk * 32), dim3(TPB), 0, stream, x, WA, c0, 1, cut, 1);
    hipLaunchKernelGGL(k_cols,     dim3(nk * 32), dim3(TPB), 0, stream, WA, WB, Abuf, Bv, Fc, c4raw, bvec, cnt, cut, c0);
    hipLaunchKernelGGL(k_rows,     dim3(nk * 64), dim3(TPB), 0, stream, WB, Abuf, bvec, c4raw, x, out, cut, c0);
  }
}

// Round 12
// 523.346 us; speedup vs baseline: 1.4900x; 1.4900x over previous
//
#include <hip/hip_runtime.h>
#include <math.h>

#define FN 512
#define TPB 256
#define NIMG 256
#define NBATCH 8
#define NCH 32
#define NBINS 257
#define WACOLS 257   // Hermitian half-spectrum columns u=0..256
#define WBS 256      // Wb row stride (complex); used width = cutoff
#define SPITCH 516   // staging/exchange row pitch (complex)

typedef unsigned long long ull;

__device__ __forceinline__ float2 cadd(float2 a, float2 b) { return make_float2(a.x + b.x, a.y + b.y); }
__device__ __forceinline__ float2 csub(float2 a, float2 b) { return make_float2(a.x - b.x, a.y - b.y); }
__device__ __forceinline__ float2 cmul(float2 a, float2 b) {
  return make_float2(fmaf(a.x, b.x, -a.y * b.y), fmaf(a.x, b.y, a.y * b.x));
}
template<bool INV>
__device__ __forceinline__ float2 cmul_s(float2 a, float2 w) {
  if (!INV) return make_float2(fmaf(a.x, w.x, -a.y * w.y), fmaf(a.x, w.y,  a.y * w.x));
  else      return make_float2(fmaf(a.x, w.x,  a.y * w.y), fmaf(a.y, w.x, -a.x * w.y));
}
__device__ __forceinline__ float2 cexpm(float ang) {
  float s, c;
  __sincosf(ang, &s, &c);
  return make_float2(c, s);
}
template<bool INV>
__device__ __forceinline__ float2 mulpmi(float2 a) {
  return INV ? make_float2(-a.y, a.x) : make_float2(a.y, -a.x);
}

template<bool INV>
__device__ __forceinline__ void dft8(float2 r[8]) {
  const float C = 0.70710678118654752440f;
  float2 t0 = cadd(r[0], r[4]), t1 = csub(r[0], r[4]);
  float2 t2 = cadd(r[2], r[6]), t3 = mulpmi<INV>(csub(r[2], r[6]));
  float2 E0 = cadd(t0, t2), E1 = cadd(t1, t3), E2 = csub(t0, t2), E3 = csub(t1, t3);
  float2 u0 = cadd(r[1], r[5]), u1 = csub(r[1], r[5]);
  float2 u2 = cadd(r[3], r[7]), u3 = mulpmi<INV>(csub(r[3], r[7]));
  float2 O0 = cadd(u0, u2), O1 = cadd(u1, u3), O2 = csub(u0, u2), O3 = csub(u1, u3);
  float2 O1w, O2w, O3w;
  if (!INV) {
    O1w = make_float2(C * (O1.x + O1.y), C * (O1.y - O1.x));
    O2w = make_float2(O2.y, -O2.x);
    O3w = make_float2(C * (O3.y - O3.x), -C * (O3.x + O3.y));
  } else {
    O1w = make_float2(C * (O1.x - O1.y), C * (O1.y + O1.x));
    O2w = make_float2(-O2.y, O2.x);
    O3w = make_float2(-C * (O3.x + O3.y), C * (O3.x - O3.y));
  }
  r[0] = cadd(E0, O0); r[1] = cadd(E1, O1w); r[2] = cadd(E2, O2w); r[3] = cadd(E3, O3w);
  r[4] = csub(E0, O0); r[5] = csub(E1, O1w); r[6] = csub(E2, O2w); r[7] = csub(E3, O3w);
}

__device__ __forceinline__ int swz(int q) {
  int b = (q >> 6) & 7;
  return q ^ b ^ ((b & 4) << 1);
}

#define TWOPI 6.2831853071795864769f

__device__ __forceinline__ void build_tw(int t, float2 tw512[7], float2 tw64[7]) {
  float2 w1 = cexpm(-TWOPI * (float)t * (1.0f / 512.0f));
  tw512[0] = w1;
  #pragma unroll
  for (int k = 1; k < 7; ++k) tw512[k] = cmul(tw512[k - 1], w1);
  float2 v1 = cexpm(-TWOPI * (float)(t & 7) * (1.0f / 64.0f));
  tw64[0] = v1;
  #pragma unroll
  for (int e = 1; e < 7; ++e) tw64[e] = cmul(tw64[e - 1], v1);
}

// Dual 512-pt FFT, natural in (reg j = x[t+64j]) -> digit-rev out
// (reg f = X[64f+8(t&7)+(t>>3)]). Wave-private exchange, no barriers.
template<bool INV>
__device__ __forceinline__ void fft512_dif2(float2 rA[8], float2 rB[8],
                                            float2* __restrict__ LA, float2* __restrict__ LB,
                                            int t, const float2 tw512[7], const float2 tw64[7]) {
  dft8<INV>(rA);
  dft8<INV>(rB);
  #pragma unroll
  for (int k = 1; k < 8; ++k) {
    rA[k] = cmul_s<INV>(rA[k], tw512[k - 1]);
    rB[k] = cmul_s<INV>(rB[k], tw512[k - 1]);
  }
  #pragma unroll
  for (int k = 0; k < 8; ++k) { LA[swz(64 * k + t)] = rA[k]; LB[swz(64 * k + t)] = rB[k]; }
  const int base = 64 * (t >> 3) + (t & 7);
  #pragma unroll
  for (int d = 0; d < 8; ++d) rA[d] = LA[swz(base + 8 * d)];
  #pragma unroll
  for (int d = 0; d < 8; ++d) rB[d] = LB[swz(base + 8 * d)];
  dft8<INV>(rA);
  dft8<INV>(rB);
  #pragma unroll
  for (int e = 1; e < 8; ++e) {
    rA[e] = cmul_s<INV>(rA[e], tw64[e - 1]);
    rB[e] = cmul_s<INV>(rB[e], tw64[e - 1]);
  }
  #pragma unroll
  for (int e = 0; e < 8; ++e) { LA[swz(base + 8 * e)] = rA[e]; LB[swz(base + 8 * e)] = rB[e]; }
  #pragma unroll
  for (int m = 0; m < 8; ++m) rA[m] = LA[swz(8 * t + m)];
  #pragma unroll
  for (int m = 0; m < 8; ++m) rB[m] = LB[swz(8 * t + m)];
  dft8<INV>(rA);
  dft8<INV>(rB);
}

// Dual mirror (DIT): digit-rev in -> natural out. INV=true gives 512*IDFT.
template<bool INV>
__device__ __forceinline__ void fft512_dit2(float2 rA[8], float2 rB[8],
                                            float2* __restrict__ LA, float2* __restrict__ LB,
                                            int t, const float2 tw64[7], float2 w0, float2 st) {
  dft8<INV>(rA);
  dft8<INV>(rB);
  #pragma unroll
  for (int c = 1; c < 8; ++c) {
    rA[c] = cmul_s<INV>(rA[c], tw64[c - 1]);
    rB[c] = cmul_s<INV>(rB[c], tw64[c - 1]);
  }
  #pragma unroll
  for (int c = 0; c < 8; ++c) { LA[swz(8 * t + c)] = rA[c]; LB[swz(8 * t + c)] = rB[c]; }
  const int base = 64 * (t >> 3) + (t & 7);
  #pragma unroll
  for (int e = 0; e < 8; ++e) rA[e] = LA[swz(base + 8 * e)];
  #pragma unroll
  for (int e = 0; e < 8; ++e) rB[e] = LB[swz(base + 8 * e)];
  dft8<INV>(rA);
  dft8<INV>(rB);
  {
    float2 w = w0;
    #pragma unroll
    for (int d = 0; d < 8; ++d) {
      rA[d] = cmul(rA[d], w);
      rB[d] = cmul(rB[d], w);
      w = cmul(w, st);
    }
  }
  #pragma unroll
  for (int d = 0; d < 8; ++d) { LA[swz(base + 8 * d)] = rA[d]; LB[swz(base + 8 * d)] = rB[d]; }
  #pragma unroll
  for (int j = 0; j < 8; ++j) rA[j] = LA[swz(64 * j + t)];
  #pragma unroll
  for (int j = 0; j < 8; ++j) rB[j] = LB[swz(64 * j + t)];
  dft8<INV>(rA);
  dft8<INV>(rB);
}

// Single FFT
template<bool INV>
__device__ __forceinline__ void fft512_dif(float2 r[8], float2* __restrict__ L, int t,
                                           const float2 tw512[7], const float2 tw64[7]) {
  dft8<INV>(r);
  #pragma unroll
  for (int k = 1; k < 8; ++k) r[k] = cmul_s<INV>(r[k], tw512[k - 1]);
  #pragma unroll
  for (int k = 0; k < 8; ++k) L[swz(64 * k + t)] = r[k];
  const int base = 64 * (t >> 3) + (t & 7);
  #pragma unroll
  for (int d = 0; d < 8; ++d) r[d] = L[swz(base + 8 * d)];
  dft8<INV>(r);
  #pragma unroll
  for (int e = 1; e < 8; ++e) r[e] = cmul_s<INV>(r[e], tw64[e - 1]);
  #pragma unroll
  for (int e = 0; e < 8; ++e) L[swz(base + 8 * e)] = r[e];
  #pragma unroll
  for (int m = 0; m < 8; ++m) r[m] = L[swz(8 * t + m)];
  dft8<INV>(r);
}

__device__ __forceinline__ int ringc(int u) { return (u < 256) ? (u + 1) : (512 - u); }

// Pass 1: two real rows packed per complex FFT (dual-interleaved pairs) -> Hermitian
// unpack -> store half spectrum transposed W[u][h], u <= ulim. 16 image rows/block.
__global__ __launch_bounds__(TPB, 4) void k_fwd_real(const float* __restrict__ x,
                                                     float2* __restrict__ W,
                                                     int img0, int img_stride,
                                                     const int* __restrict__ cut, int use_cut) {
  __shared__ float2 stg[8][SPITCH];
  const int g = threadIdx.x >> 6, t = threadIdx.x & 63;
  const int li = blockIdx.x >> 5;
  const int R0 = (blockIdx.x & 31) * 16;
  const int img = img0 + li * img_stride;
  int ulim = 256;
  if (use_cut) ulim = cut[img >> 5];
  const float* __restrict__ base = x + (size_t)img * (FN * FN);
  float2 tw512[7], tw64[7];
  build_tw(t, tw512, tw64);
  {
    const float* __restrict__ raA = base + (size_t)(R0 + 2 * g) * FN;
    const float* __restrict__ rbA = raA + FN;
    const float* __restrict__ raB = base + (size_t)(R0 + 8 + 2 * g) * FN;
    const float* __restrict__ rbB = raB + FN;
    float2 rA[8], rB[8];
    #pragma unroll
    for (int j = 0; j < 8; ++j) {
      rA[j] = make_float2(raA[t + 64 * j], rbA[t + 64 * j]);
      rB[j] = make_float2(raB[t + 64 * j], rbB[t + 64 * j]);
    }
    fft512_dif2<false>(rA, rB, &stg[g][0], &stg[4 + g][0], t, tw512, tw64);
    #pragma unroll
    for (int f = 0; f < 8; ++f) {
      int p = 64 * f + 8 * (t & 7) + (t >> 3);
      stg[g][p] = rA[f];
      stg[4 + g][p] = rB[f];
    }
  }
  __syncthreads();
  float2* __restrict__ dst = W + (size_t)li * (WACOLS * FN);
  const int pr = threadIdx.x & 7;
  const int u0 = threadIdx.x >> 3;
  #pragma unroll
  for (int kk = 0; kk < 8; ++kk) {
    int u = u0 + 32 * kk;
    if (u <= ulim) {
      float2 Za = stg[pr][u];
      float2 Zb = stg[pr][(512 - u) & 511];
      float2 Fa = make_float2(0.5f * (Za.x + Zb.x), 0.5f * (Za.y - Zb.y));
      float2 Fb = make_float2(0.5f * (Za.y + Zb.y), 0.5f * (Zb.x - Za.x));
      float4* d4 = (float4*)(dst + (size_t)u * FN + R0 + 2 * pr);
      *d4 = make_float4(Fa.x, Fa.y, Fb.x, Fb.y);
    }
  }
  if (!use_cut && threadIdx.x < 8) {               // u=256 Nyquist (prepass only)
    float2 Z = stg[threadIdx.x][256];
    float4* d4 = (float4*)(dst + (size_t)256 * FN + R0 + 2 * threadIdx.x);
    *d4 = make_float4(Z.x, 0.f, Z.y, 0.f);
  }
}

// Pre-pass: ring energies (fixed-point, order-invariant) -> cutoffs.
__global__ __launch_bounds__(TPB) void k_ring(const float2* __restrict__ W1p, ull* __restrict__ bins) {
  __shared__ float2 ex[4][FN];
  __shared__ ull lbins[NBINS];
  const int g = threadIdx.x >> 6, t = threadIdx.x & 63;
  for (int i = threadIdx.x; i < NBINS; i += TPB) lbins[i] = 0;
  __syncthreads();
  const int li = blockIdx.x / 33;
  const int U0 = (blockIdx.x % 33) * 8;
  const float2* __restrict__ src = W1p + (size_t)li * (WACOLS * FN);
  float2 tw512[7], tw64[7];
  build_tw(t, tw512, tw64);
  #pragma unroll
  for (int s = 0; s < 2; ++s) {
    const int u = U0 + 4 * s + g;
    if (u > 256) continue;
    const float2* __restrict__ row = src + (size_t)u * FN;
    float2 r[8];
    #pragma unroll
    for (int j = 0; j < 8; ++j) r[j] = row[t + 64 * j];
    fft512_dif<false>(r, &ex[g][0], t, tw512, tw64);
    const int cu = ringc(u);
    const bool mir = (u >= 1 && u <= 255);
    const int cmu = mir ? ringc(512 - u) : 0;
    #pragma unroll
    for (int f = 0; f < 8; ++f) {
      int v = 64 * f + 8 * (t & 7) + (t >> 3);
      float e = fmaf(r[f].x, r[f].x, r[f].y * r[f].y);
      ull q = (ull)((double)e * 1048576.0);
      atomicAdd(&lbins[max(cu, ringc(v))], q);
      if (mir) atomicAdd(&lbins[max(cmu, ringc((512 - v) & 511))], q);
    }
  }
  __syncthreads();
  for (int i = threadIdx.x; i < NBINS; i += TPB)
    if (lbins[i]) atomicAdd(&bins[(size_t)li * NBINS + i], lbins[i]);
}

__global__ __launch_bounds__(64) void k_cutoff(const ull* __restrict__ bins, int* __restrict__ cut) {
  int b = threadIdx.x;
  if (b >= NBATCH) return;
  double tot = 0.0;
  for (int r = 0; r < NBINS; ++r) tot += (double)bins[b * NBINS + r];
  double target = 0.5 * tot;
  double cum = 0.0;
  int c = 5;
  bool found = false;
  for (int r = 0; r <= 255; ++r) {
    cum += (double)bins[b * NBINS + r];
    if (r >= 1 && !found && cum >= target) { c = r; found = true; }
  }
  cut[b] = c;
}

// Pass 2 (symmetric-mask primaries u in [0,cut]): column FFT -> extract F(cut,u),
// F(NC,u) -> symmetric lvs mask (scaled 1/512) -> inverse column FFT.
// u<cut -> Wb[h][u]; u==cut -> Abuf[h]. NC = 512-cut.
__global__ __launch_bounds__(TPB, 4) void k_cols(const float2* __restrict__ Wa,
                                                 float2* __restrict__ Wb,
                                                 float2* __restrict__ Abuf,
                                                 float2* __restrict__ Bv,
                                                 float2* __restrict__ Fc,
                                                 float2* __restrict__ c4raw,
                                                 const int* __restrict__ cut, int img0) {
  __shared__ float2 stg[8][SPITCH];
  const int g = threadIdx.x >> 6, t = threadIdx.x & 63;
  const int li = blockIdx.x >> 5;
  const int U0 = (blockIdx.x & 31) * 8;
  const int cutoff = cut[(img0 + li) >> 5];
  const int NC = 512 - cutoff;
  if (U0 > cutoff) return;
  const float2* __restrict__ src = Wa + (size_t)li * (WACOLS * FN);
  float2 tw512[7], tw64[7];
  build_tw(t, tw512, tw64);
  const int tk = t >> 3, tc = t & 7;
  const float2 w0d = cexpm(TWOPI * (float)(tc * tk) * (1.0f / 512.0f));
  const float2 std = cexpm(TWOPI * (float)tk * (1.0f / 64.0f));
  const float sc = 1.0f / 512.0f;
  const int uA = U0 + g, uB = U0 + 4 + g;
  const float2* __restrict__ rowA = src + (size_t)uA * FN;
  const float2* __restrict__ rowB = src + (size_t)uB * FN;
  float2 rA[8], rB[8];
  #pragma unroll
  for (int j = 0; j < 8; ++j) { rA[j] = rowA[t + 64 * j]; rB[j] = rowB[t + 64 * j]; }
  float2* LA = &stg[g][0];
  float2* LB = &stg[4 + g][0];
  fft512_dif2<false>(rA, rB, LA, LB, t, tw512, tw64);
  const int vt = 8 * tc + tk;
  #pragma unroll
  for (int f = 0; f < 8; ++f) {
    int v = 64 * f + vt;
    if (v == cutoff) {
      if (uA < cutoff) Fc[li * 256 + uA] = rA[f];
      else if (uA == cutoff) c4raw[li] = rA[f];
      if (uB < cutoff) Fc[li * 256 + uB] = rB[f];
      else if (uB == cutoff) c4raw[li] = rB[f];
    }
    if (v == NC) {
      if (uA < cutoff) Bv[li * 256 + uA] = rA[f];
      if (uB < cutoff) Bv[li * 256 + uB] = rB[f];
    }
  }
  #pragma unroll
  for (int f = 0; f < 8; ++f) {
    int v = 64 * f + vt;
    bool lo = (v < cutoff) || (v > NC);
    rA[f] = lo ? make_float2(rA[f].x * sc, rA[f].y * sc) : make_float2(0.f, 0.f);
    rB[f] = lo ? make_float2(rB[f].x * sc, rB[f].y * sc) : make_float2(0.f, 0.f);
  }
  fft512_dit2<true>(rA, rB, LA, LB, t, tw64, w0d, std);
  const bool aA = (uA == cutoff), aB = (uB == cutoff);
  #pragma unroll
  for (int j = 0; j < 8; ++j) {
    int h = t + 64 * j;
    stg[g][h] = rA[j];
    stg[4 + g][h] = rB[j];
    if (aA) Abuf[li * 512 + h] = rA[j];
    if (aB) Abuf[li * 512 + h] = rB[j];
  }
  __syncthreads();
  float2* __restrict__ dst = Wb + (size_t)li * (512 * WBS);
  const int rl2 = threadIdx.x & 3;
  const int hg = threadIdx.x >> 2;
  #pragma unroll
  for (int kk = 0; kk < 8; ++kk) {
    int h = hg + 64 * kk;
    float2 a = stg[2 * rl2][h];
    float2 b = stg[2 * rl2 + 1][h];
    float4* d4 = (float4*)(dst + (size_t)h * WBS + U0 + 2 * rl2);
    *d4 = make_float4(a.x, a.y, b.x, b.y);
  }
}

// Build Gv (u-spectrum of b) from Bv/Fc and transform with ONE 512-FFT per image:
// b(w) = sum_u Gv[u] e^{+2pi i uw/512}; Gv[u<cut]=Bv[u]/512^2,
// Gv[u>=513-cut]=conj(Fc[512-u])/512^2, else 0. One wave per image.
__global__ __launch_bounds__(64) void k_gv(const float2* __restrict__ Bv,
                                           const float2* __restrict__ Fc,
                                           float2* __restrict__ bvec,
                                           const int* __restrict__ cut, int img0) {
  __shared__ float2 ex[SPITCH];
  const int t = threadIdx.x;
  const int li = blockIdx.x;
  const int cutoff = cut[(img0 + li) >> 5];
  const float s2 = 1.0f / (512.0f * 512.0f);
  float2 tw512[7], tw64[7];
  build_tw(t, tw512, tw64);
  float2 r[8];
  #pragma unroll
  for (int j = 0; j < 8; ++j) {
    int u = t + 64 * j;
    float2 gv = make_float2(0.f, 0.f);
    if (u < cutoff) {
      float2 b = Bv[li * 256 + u];
      gv = make_float2(b.x * s2, b.y * s2);
    } else if (u >= 513 - cutoff) {
      float2 F = Fc[li * 256 + (512 - u)];
      gv = make_float2(F.x * s2, -F.y * s2);
    }
    r[j] = gv;
  }
  fft512_dif<true>(r, ex, t, tw512, tw64);
  #pragma unroll
  for (int f = 0; f < 8; ++f) {
    int w = 64 * f + 8 * (t & 7) + (t >> 3);
    bvec[li * 512 + w] = r[f];
  }
}

// Pass 3 (slim): one packed-row IFFT per wave (rows h1,h2). Hermitian-extend Wb,
// inverse FFT, add corrections d = ph*A' + wv*b, out = |x - low - d|.
__global__ __launch_bounds__(TPB, 4) void k_rows(const float2* __restrict__ Wb,
                                                 const float2* __restrict__ Abuf,
                                                 const float2* __restrict__ bvec,
                                                 const float2* __restrict__ c4raw,
                                                 const float* __restrict__ x,
                                                 float* __restrict__ out,
                                                 const int* __restrict__ cut, int img0) {
  __shared__ float2 ex[4][SPITCH];
  const int g = threadIdx.x >> 6, t = threadIdx.x & 63;
  const int li = blockIdx.x >> 6;
  const int H0 = (blockIdx.x & 63) * 8;
  const int img = img0 + li;
  const int cutoff = cut[img >> 5];
  const int NC = 512 - cutoff;
  const float2* __restrict__ wbase = Wb + (size_t)li * (512 * WBS);
  const float* __restrict__ xbase = x + (size_t)img * (FN * FN);
  float* __restrict__ obase = out + (size_t)img * (FN * FN);
  float2 tw512[7], tw64[7];
  build_tw(t, tw512, tw64);
  const float sc = 1.0f / 512.0f;
  const int h1 = H0 + 2 * g, h2 = h1 + 1;
  const float2* __restrict__ r1 = wbase + (size_t)h1 * WBS;
  const float2* __restrict__ r2 = wbase + (size_t)h2 * WBS;
  float2 r[8];
  #pragma unroll
  for (int j = 0; j < 8; ++j) {
    int u = t + 64 * j;
    float2 z;
    if (u < cutoff) {
      float2 m1 = r1[u], m2 = r2[u];
      z = make_float2(m1.x - m2.y, m1.y + m2.x);
    } else if (u > NC) {
      int um = 512 - u;
      float2 m1 = r1[um], m2 = r2[um];
      z = make_float2(m1.x + m2.y, -m1.y + m2.x);
    } else {
      z = make_float2(0.f, 0.f);
    }
    r[j] = make_float2(z.x * sc, z.y * sc);
  }
  fft512_dif<true>(r, &ex[g][0], t, tw512, tw64);
  // per-row correction scalars
  const float s2 = sc * sc;
  float2 cv = c4raw[li];
  const float2 c4 = make_float2(cv.x * s2, -cv.y * s2);
  float2 wv1 = cexpm(TWOPI * (float)((NC * h1) & 511) * (1.0f / 512.0f));
  float2 wv2 = cexpm(TWOPI * (float)((NC * h2) & 511) * (1.0f / 512.0f));
  float2 A1 = Abuf[li * 512 + h1], A2 = Abuf[li * 512 + h2];
  float2 A1p = cadd(make_float2(A1.x * sc, -A1.y * sc), cmul(c4, wv1));
  float2 A2p = cadd(make_float2(A2.x * sc, -A2.y * sc), cmul(c4, wv2));
  const int w0i = 8 * (t & 7) + (t >> 3);
  float2 ph = cexpm(TWOPI * (float)((NC * w0i) & 511) * (1.0f / 512.0f));
  const float2 s64 = cexpm(TWOPI * (float)((64 * (NC & 7)) & 511) * (1.0f / 512.0f));
  const float* __restrict__ x1 = xbase + (size_t)h1 * FN;
  const float* __restrict__ x2 = xbase + (size_t)h2 * FN;
  float* __restrict__ o1 = obase + (size_t)h1 * FN;
  float* __restrict__ o2 = obase + (size_t)h2 * FN;
  const float2* __restrict__ bp = bvec + li * 512;
  #pragma unroll
  for (int f = 0; f < 8; ++f) {
    int p = 64 * f + w0i;
    float2 bv = bp[p];
    float2 d1 = cadd(cmul(ph, A1p), cmul(wv1, bv));
    float2 d2 = cadd(cmul(ph, A2p), cmul(wv2, bv));
    float e1 = x1[p] - r[f].x - d1.x;
    float e2 = x2[p] - r[f].y - d2.x;
    o1[p] = sqrtf(fmaf(e1, e1, d1.y * d1.y));
    o2[p] = sqrtf(fmaf(e2, e2, d2.y * d2.y));
    ph = cmul(ph, s64);
  }
}

extern "C" void kernel_launch(void* const* d_in, const int* in_sizes, int n_in,
                              void* d_out, int out_size, void* d_ws, size_t ws_size,
                              hipStream_t stream) {
  const float* x = (const float*)d_in[0];
  float* out = (float*)d_out;
  char* ws = (char*)d_ws;

  size_t off = 0;
  ull* bins = (ull*)(ws + off);
  off += ((size_t)NBATCH * NBINS * sizeof(ull) + 255) & ~(size_t)255;
  int* cut = (int*)(ws + off);
  off += 256;
  float2* W1p = (float2*)(ws + off);
  off += (size_t)NBATCH * WACOLS * FN * sizeof(float2);        // 8.4 MiB

  const size_t per_wa = (size_t)WACOLS * FN * sizeof(float2);  // ~1.03 MiB
  const size_t per_wb = (size_t)512 * WBS * sizeof(float2);    // 1 MiB
  const size_t per_side = (size_t)(512 + 512 + 256 + 256 + 8) * sizeof(float2);
  size_t avail = (ws_size > off) ? (ws_size - off) : 0;
  int K = (int)(avail / (per_wa + per_wb + per_side));
  if (K > 32) K = 32;   // keep everything L3-resident
  if (K < 1) K = 1;
  float2* WA = (float2*)(ws + off);               off += (size_t)K * per_wa;
  float2* WB = (float2*)(ws + off);               off += (size_t)K * per_wb;
  float2* Abuf = (float2*)(ws + off);             off += (size_t)K * 512 * sizeof(float2);
  float2* bvec = (float2*)(ws + off);             off += (size_t)K * 512 * sizeof(float2);
  float2* Bv = (float2*)(ws + off);               off += (size_t)K * 256 * sizeof(float2);
  float2* Fc = (float2*)(ws + off);               off += (size_t)K * 256 * sizeof(float2);
  float2* c4raw = (float2*)(ws + off);            off += (size_t)K * 8 * sizeof(float2);

  hipMemsetAsync(bins, 0, (size_t)NBATCH * NBINS * sizeof(ull), stream);

  // Pre-pass on the 8 channel-0 images: half-spectrum + ring energies + cutoffs.
  hipLaunchKernelGGL(k_fwd_real, dim3(NBATCH * 32), dim3(TPB), 0, stream, x, W1p, 0, NCH, cut, 0);
  hipLaunchKernelGGL(k_ring,     dim3(NBATCH * 33), dim3(TPB), 0, stream, W1p, bins);
  hipLaunchKernelGGL(k_cutoff,   dim3(1),           dim3(64),  0, stream, bins, cut);

  // Main pipeline, chunked for L3 residency.
  for (int c0 = 0; c0 < NIMG; c0 += K) {
    int nk = (NIMG - c0 < K) ? (NIMG - c0) : K;
    hipLaunchKernelGGL(k_fwd_real, dim3(nk * 32), dim3(TPB), 0, stream, x, WA, c0, 1, cut, 1);
    hipLaunchKernelGGL(k_cols,     dim3(nk * 32), dim3(TPB), 0, stream, WA, WB, Abuf, Bv, Fc, c4raw, cut, c0);
    hipLaunchKernelGGL(k_gv,       dim3(nk),      dim3(64),  0, stream, Bv, Fc, bvec, cut, c0);
    hipLaunchKernelGGL(k_rows,     dim3(nk * 64), dim3(TPB), 0, stream, WB, Abuf, bvec, c4raw, x, out, cut, c0);
  }
}